// Round 2
// baseline (7459.292 us; speedup 1.0000x reference)
//
#include <hip/hip_runtime.h>

typedef unsigned short u16;
typedef __attribute__((ext_vector_type(8))) short vbf16x8;   // 8 bf16 (4 VGPRs)
typedef __attribute__((ext_vector_type(4))) float vf32x4;    // MFMA acc frag

__device__ __forceinline__ float bf2f(u16 u) {
    union { unsigned int i; float f; } v; v.i = ((unsigned int)u) << 16; return v.f;
}
__device__ __forceinline__ u16 f2bf(float f) {
    union { float f; unsigned int i; } v; v.f = f;
    return (u16)((v.i + 0x7fffu + ((v.i >> 16) & 1u)) >> 16);  // RNE
}
__device__ __forceinline__ void atomAddF(float* p, float v) {
    __hip_atomic_fetch_add(p, v, __ATOMIC_RELAXED, __HIP_MEMORY_SCOPE_AGENT);
}

// ---------------- degree count ----------------
__global__ __launch_bounds__(256) void deg_kernel(
    const int* __restrict__ src, const int* __restrict__ dst,
    float* __restrict__ degd, float* __restrict__ dega, int E) {
    int e = blockIdx.x * 256 + threadIdx.x;
    if (e >= E) return;
    atomAddF(degd + src[e], 1.0f);
    atomAddF(dega + dst[e], 1.0f);
}

// ------------- 128x128 weight transposes f32 -> bf16 (9 mats) -------------
struct TPack { const float* src[9]; u16* dst[9]; };
__global__ __launch_bounds__(256) void transpose_all(TPack p) {
    int mat = blockIdx.y;
    const float* s = p.src[mat];
    u16* d = p.dst[mat];
    int i = blockIdx.x * 256 + threadIdx.x;   // gridDim.x = 64 -> 16384 elems
    int k = i >> 7, n = i & 127;
    d[(size_t)n * 128 + k] = f2bf(s[(size_t)k * 128 + n]);  // WT[n][k] = W[k][n]
}

// ------------- row gather + f32->bf16 (x_author = emb[ids]) ---------------
__global__ __launch_bounds__(256) void gather_rows(
    const float* __restrict__ src, const int* __restrict__ ids,
    u16* __restrict__ out, int N) {
    int gid = blockIdx.x * 256 + threadIdx.x;
    if (gid >= N * 16) return;
    int n = gid >> 4, f = gid & 15;
    int id = ids[n];
    const float* s = src + (size_t)id * 128 + f * 8;
    float4 lo = *(const float4*)(s);
    float4 hi = *(const float4*)(s + 4);
    u16 o[8] = {f2bf(lo.x), f2bf(lo.y), f2bf(lo.z), f2bf(lo.w),
                f2bf(hi.x), f2bf(hi.y), f2bf(hi.z), f2bf(hi.w)};
    *(uint4*)(out + (size_t)n * 128 + f * 8) = *(const uint4*)o;
}

// ---------------- edge scatter-add: agg[dst] += xsrc[src] ----------------
__global__ __launch_bounds__(256) void scatter_add_kernel(
    const u16* __restrict__ xsrc, const int* __restrict__ src,
    const int* __restrict__ dst, float* __restrict__ agg, int E) {
    int gid = blockIdx.x * 256 + threadIdx.x;
    if (gid >= E * 16) return;
    int e = gid >> 4, f = gid & 15;
    int s = src[e], d = dst[e];
    uint4 q = *(const uint4*)(xsrc + (size_t)s * 128 + f * 8);
    float* o = agg + (size_t)d * 128 + f * 8;
    atomAddF(o + 0, bf2f((u16)(q.x & 0xffff)));
    atomAddF(o + 1, bf2f((u16)(q.x >> 16)));
    atomAddF(o + 2, bf2f((u16)(q.y & 0xffff)));
    atomAddF(o + 3, bf2f((u16)(q.y >> 16)));
    atomAddF(o + 4, bf2f((u16)(q.z & 0xffff)));
    atomAddF(o + 5, bf2f((u16)(q.z >> 16)));
    atomAddF(o + 6, bf2f((u16)(q.w & 0xffff)));
    atomAddF(o + 7, bf2f((u16)(q.w >> 16)));
}

// ---------------- fused SAGE output GEMM ----------------
// out[M,128] = maybe_relu( (A1/deg) @ W1 + A2 @ W2 + bias )
// A1 path: f32 rows (scatter accumulator or raw f32 input), normalized by
//          deg if deg != null, converted to bf16 fragments on load.
// W*T are pre-transposed [n][k] bf16 so B-frags are contiguous 16B loads.
// MFMA 16x16x32 bf16: A[m=lane&15][k=(lane>>4)*8+j]; C/D col=lane&15,
// row=(lane>>4)*4+r  (per guide §3, m89/m91-verified).
__global__ __launch_bounds__(256) void sage_gemm(
    const float* __restrict__ A1f, const float* __restrict__ deg,
    const u16* __restrict__ W1T,
    const u16* __restrict__ A2b, const u16* __restrict__ W2T,
    const float* __restrict__ bias, const int do_relu,
    u16* __restrict__ out, const int M) {
    const int lane = threadIdx.x & 63;
    const int wave = threadIdx.x >> 6;
    const int m0 = (blockIdx.x * 4 + wave) * 16;   // 16 rows per wave
    if (m0 >= M) return;                            // M % 16 == 0 for all calls
    const int r15 = lane & 15;
    const int kq = lane >> 4;
    const int m = m0 + r15;

    vf32x4 acc[8];
#pragma unroll
    for (int i = 0; i < 8; ++i) acc[i] = (vf32x4)(0.0f);

    {
        const float inv = deg ? (1.0f / fmaxf(deg[m], 1.0f)) : 1.0f;
        const float* arow = A1f + (size_t)m * 128 + kq * 8;
#pragma unroll
        for (int ks = 0; ks < 4; ++ks) {
            const float4 lo = *(const float4*)(arow + ks * 32);
            const float4 hi = *(const float4*)(arow + ks * 32 + 4);
            vbf16x8 a;
            a[0] = (short)f2bf(lo.x * inv); a[1] = (short)f2bf(lo.y * inv);
            a[2] = (short)f2bf(lo.z * inv); a[3] = (short)f2bf(lo.w * inv);
            a[4] = (short)f2bf(hi.x * inv); a[5] = (short)f2bf(hi.y * inv);
            a[6] = (short)f2bf(hi.z * inv); a[7] = (short)f2bf(hi.w * inv);
#pragma unroll
            for (int nt = 0; nt < 8; ++nt) {
                vbf16x8 b = *(const vbf16x8*)(W1T + (size_t)(nt * 16 + r15) * 128 + ks * 32 + kq * 8);
                acc[nt] = __builtin_amdgcn_mfma_f32_16x16x32_bf16(a, b, acc[nt], 0, 0, 0);
            }
        }
    }

    if (A2b) {
        const u16* arow = A2b + (size_t)m * 128 + kq * 8;
#pragma unroll
        for (int ks = 0; ks < 4; ++ks) {
            vbf16x8 a = *(const vbf16x8*)(arow + ks * 32);
#pragma unroll
            for (int nt = 0; nt < 8; ++nt) {
                vbf16x8 b = *(const vbf16x8*)(W2T + (size_t)(nt * 16 + r15) * 128 + ks * 32 + kq * 8);
                acc[nt] = __builtin_amdgcn_mfma_f32_16x16x32_bf16(a, b, acc[nt], 0, 0, 0);
            }
        }
    }

    // epilogue: bias + optional relu, write bf16
#pragma unroll
    for (int nt = 0; nt < 8; ++nt) {
        const float bv = bias ? bias[nt * 16 + r15] : 0.0f;
#pragma unroll
        for (int r = 0; r < 4; ++r) {
            float v = acc[nt][r] + bv;
            if (do_relu) v = fmaxf(v, 0.0f);
            out[(size_t)(m0 + kq * 4 + r) * 128 + nt * 16 + r15] = f2bf(v);
        }
    }
}

// ---------------- edge scorer: pred[e] = dot(od[i0[e]], oa[i1[e]]) --------
__global__ __launch_bounds__(256) void edge_dot(
    const u16* __restrict__ od, const u16* __restrict__ oa,
    const int* __restrict__ i0, const int* __restrict__ i1,
    float* __restrict__ pred, int EL) {
    int gid = blockIdx.x * 256 + threadIdx.x;
    if (gid >= EL * 16) return;
    int e = gid >> 4, f = gid & 15;
    uint4 x = *(const uint4*)(od + (size_t)i0[e] * 128 + f * 8);
    uint4 y = *(const uint4*)(oa + (size_t)i1[e] * 128 + f * 8);
    float s = 0.0f;
    s += bf2f((u16)(x.x & 0xffff)) * bf2f((u16)(y.x & 0xffff));
    s += bf2f((u16)(x.x >> 16))    * bf2f((u16)(y.x >> 16));
    s += bf2f((u16)(x.y & 0xffff)) * bf2f((u16)(y.y & 0xffff));
    s += bf2f((u16)(x.y >> 16))    * bf2f((u16)(y.y >> 16));
    s += bf2f((u16)(x.z & 0xffff)) * bf2f((u16)(y.z & 0xffff));
    s += bf2f((u16)(x.z >> 16))    * bf2f((u16)(y.z >> 16));
    s += bf2f((u16)(x.w & 0xffff)) * bf2f((u16)(y.w & 0xffff));
    s += bf2f((u16)(x.w >> 16))    * bf2f((u16)(y.w >> 16));
    // reduce across the 16 lanes sharing e (xor bits 0..3 stay in-group)
    s += __shfl_xor(s, 1);
    s += __shfl_xor(s, 2);
    s += __shfl_xor(s, 4);
    s += __shfl_xor(s, 8);
    if (f == 0) pred[e] = s;
}

extern "C" void kernel_launch(void* const* d_in, const int* in_sizes, int n_in,
                              void* d_out, int out_size, void* d_ws, size_t ws_size,
                              hipStream_t stream) {
    const float* doc_x    = (const float*)d_in[0];
    const int*   auth_id  = (const int*)d_in[1];
    const int*   eidx     = (const int*)d_in[2];
    const int*   elidx    = (const int*)d_in[3];
    const float* W_doc    = (const float*)d_in[4];
    const float* b_doc    = (const float*)d_in[5];
    const float* emb      = (const float*)d_in[6];
    const float* c1_da_Wl = (const float*)d_in[7];
    const float* c1_da_bl = (const float*)d_in[8];
    const float* c1_da_Wr = (const float*)d_in[9];
    const float* c1_ad_Wl = (const float*)d_in[10];
    const float* c1_ad_bl = (const float*)d_in[11];
    const float* c1_ad_Wr = (const float*)d_in[12];
    const float* c2_da_Wl = (const float*)d_in[13];
    const float* c2_da_bl = (const float*)d_in[14];
    const float* c2_da_Wr = (const float*)d_in[15];
    const float* c2_ad_Wl = (const float*)d_in[16];
    const float* c2_ad_bl = (const float*)d_in[17];
    const float* c2_ad_Wr = (const float*)d_in[18];

    const int ND = in_sizes[0] / 128;
    const int NA = in_sizes[1];
    const int E  = in_sizes[2] / 2;
    const int EL = in_sizes[3] / 2;
    const int* e_src = eidx;        // doc endpoints
    const int* e_dst = eidx + E;    // author endpoints

    // ---- workspace layout (~129 MB) ----
    char* base = (char*)d_ws;
    size_t off = 0;
    auto alloc = [&](size_t bytes) {
        void* p = base + off;
        off = (off + bytes + 255) & ~(size_t)255;
        return p;
    };
    u16*  xdoc  = (u16*)alloc((size_t)ND * 128 * 2);   // later reused as o_d
    u16*  xauth = (u16*)alloc((size_t)NA * 128 * 2);   // later reused as o_a
    u16*  hd    = (u16*)alloc((size_t)ND * 128 * 2);
    u16*  ha    = (u16*)alloc((size_t)NA * 128 * 2);
    float* agg  = (float*)alloc((size_t)ND * 128 * 4);
    float* degd = (float*)alloc((size_t)ND * 4);
    float* dega = (float*)alloc((size_t)NA * 4);
    u16*  wt    = (u16*)alloc((size_t)9 * 128 * 128 * 2);
    (void)ws_size; (void)n_in; (void)out_size;
    u16* od = xdoc;   // layer-2 outputs overwrite layer-0 features
    u16* oa = xauth;

    // ---- degrees (shared by both layers) ----
    hipMemsetAsync(degd, 0, (size_t)ND * 4, stream);
    hipMemsetAsync(dega, 0, (size_t)NA * 4, stream);
    deg_kernel<<<(E + 255) / 256, 256, 0, stream>>>(e_src, e_dst, degd, dega, E);

    // ---- weight transposes (f32 -> bf16) ----
    TPack tp;
    const float* srcs[9] = {W_doc, c1_da_Wl, c1_da_Wr, c1_ad_Wl, c1_ad_Wr,
                            c2_da_Wl, c2_da_Wr, c2_ad_Wl, c2_ad_Wr};
    for (int i = 0; i < 9; ++i) { tp.src[i] = srcs[i]; tp.dst[i] = wt + (size_t)i * 16384; }
    transpose_all<<<dim3(64, 9), 256, 0, stream>>>(tp);
    const u16 *WTdoc = wt, *WT_c1daL = wt + 16384, *WT_c1daR = wt + 2 * 16384,
              *WT_c1adL = wt + 3 * 16384, *WT_c1adR = wt + 4 * 16384,
              *WT_c2daL = wt + 5 * 16384, *WT_c2daR = wt + 6 * 16384,
              *WT_c2adL = wt + 7 * 16384, *WT_c2adR = wt + 8 * 16384;

    // ---- node features ----
    gather_rows<<<(NA * 16 + 255) / 256, 256, 0, stream>>>(emb, auth_id, xauth, NA);
    // doc encoder: xdoc = doc_x @ W_doc + b_doc   (A1f = f32 doc_x, no deg)
    sage_gemm<<<(ND + 63) / 64, 256, 0, stream>>>(
        doc_x, nullptr, WTdoc, nullptr, nullptr, b_doc, 0, xdoc, ND);

    // ---- layer 1: doc->author  (h_a, relu) ----
    hipMemsetAsync(agg, 0, (size_t)NA * 128 * 4, stream);
    scatter_add_kernel<<<(E * 16 + 255) / 256, 256, 0, stream>>>(xdoc, e_src, e_dst, agg, E);
    sage_gemm<<<(NA + 63) / 64, 256, 0, stream>>>(
        agg, dega, WT_c1daL, xauth, WT_c1daR, c1_da_bl, 1, ha, NA);

    // ---- layer 1: author->doc  (h_d, relu) ----
    hipMemsetAsync(agg, 0, (size_t)ND * 128 * 4, stream);
    scatter_add_kernel<<<(E * 16 + 255) / 256, 256, 0, stream>>>(xauth, e_dst, e_src, agg, E);
    sage_gemm<<<(ND + 63) / 64, 256, 0, stream>>>(
        agg, degd, WT_c1adL, xdoc, WT_c1adR, c1_ad_bl, 1, hd, ND);

    // ---- layer 2: doc->author  (o_a) ----
    hipMemsetAsync(agg, 0, (size_t)NA * 128 * 4, stream);
    scatter_add_kernel<<<(E * 16 + 255) / 256, 256, 0, stream>>>(hd, e_src, e_dst, agg, E);
    sage_gemm<<<(NA + 63) / 64, 256, 0, stream>>>(
        agg, dega, WT_c2daL, ha, WT_c2daR, c2_da_bl, 0, oa, NA);

    // ---- layer 2: author->doc  (o_d) ----
    hipMemsetAsync(agg, 0, (size_t)ND * 128 * 4, stream);
    scatter_add_kernel<<<(E * 16 + 255) / 256, 256, 0, stream>>>(ha, e_dst, e_src, agg, E);
    sage_gemm<<<(ND + 63) / 64, 256, 0, stream>>>(
        agg, degd, WT_c2adL, hd, WT_c2adR, c2_ad_bl, 0, od, ND);

    // ---- edge scorer ----
    edge_dot<<<(EL * 16 + 255) / 256, 256, 0, stream>>>(
        od, oa, elidx, elidx + EL, (float*)d_out, EL);
}

// Round 3
// 608.594 us; speedup vs baseline: 12.2566x; 12.2566x over previous
//
#include <hip/hip_runtime.h>

typedef unsigned short u16;
typedef __attribute__((ext_vector_type(8))) short vbf16x8;   // 8 bf16 (4 VGPRs)
typedef __attribute__((ext_vector_type(4))) float vf32x4;    // MFMA acc frag

__device__ __forceinline__ float bf2f(u16 u) {
    union { unsigned int i; float f; } v; v.i = ((unsigned int)u) << 16; return v.f;
}
__device__ __forceinline__ u16 f2bf(float f) {
    union { float f; unsigned int i; } v; v.f = f;
    return (u16)((v.i + 0x7fffu + ((v.i >> 16) & 1u)) >> 16);  // RNE
}

// ================= CSR build =================
__global__ __launch_bounds__(256) void hist_kernel(
    const int* __restrict__ src, const int* __restrict__ dst,
    int* __restrict__ cnt_d, int* __restrict__ cnt_a, int E) {
    int e = blockIdx.x * 256 + threadIdx.x;
    if (e >= E) return;
    atomicAdd(cnt_d + src[e], 1);
    atomicAdd(cnt_a + dst[e], 1);
}

// inclusive scan within 256-blocks + block sums
__global__ __launch_bounds__(256) void scan1(
    const int* __restrict__ in, int* __restrict__ incl,
    int* __restrict__ bsums, int N) {
    __shared__ int sh[256];
    int tid = threadIdx.x, gid = blockIdx.x * 256 + tid;
    int v = gid < N ? in[gid] : 0;
    sh[tid] = v; __syncthreads();
    for (int off = 1; off < 256; off <<= 1) {
        int t = tid >= off ? sh[tid - off] : 0; __syncthreads();
        sh[tid] += t; __syncthreads();
    }
    if (gid < N) incl[gid] = sh[tid];
    if (tid == 255) bsums[blockIdx.x] = sh[255];
}

// single-block exclusive scan of block sums (nb <= few hundred)
__global__ __launch_bounds__(256) void scan2(int* __restrict__ bs, int nb) {
    __shared__ int sh[256];
    __shared__ int carry;
    int tid = threadIdx.x;
    if (tid == 0) carry = 0;
    __syncthreads();
    for (int base = 0; base < nb; base += 256) {
        int i = base + tid;
        int v = i < nb ? bs[i] : 0;
        sh[tid] = v; __syncthreads();
        for (int off = 1; off < 256; off <<= 1) {
            int t = tid >= off ? sh[tid - off] : 0; __syncthreads();
            sh[tid] += t; __syncthreads();
        }
        if (i < nb) bs[i] = carry + sh[tid] - v;   // exclusive
        __syncthreads();
        if (tid == 255) carry += sh[255];
        __syncthreads();
    }
}

// offsets[i+1] = incl[i] + block_offset ; offsets[0] = 0
__global__ __launch_bounds__(256) void scan3(
    const int* __restrict__ incl, const int* __restrict__ bsoff,
    int* __restrict__ offs, int N) {
    int gid = blockIdx.x * 256 + threadIdx.x;
    if (gid < N) offs[gid + 1] = incl[gid] + bsoff[blockIdx.x];
    if (gid == 0) offs[0] = 0;
}

// place each edge into both adjacency lists via atomic cursors
__global__ __launch_bounds__(256) void fill_kernel(
    const int* __restrict__ src, const int* __restrict__ dst,
    int* __restrict__ cur_d, int* __restrict__ cur_a,
    int* __restrict__ nbr_d, int* __restrict__ nbr_a, int E) {
    int e = blockIdx.x * 256 + threadIdx.x;
    if (e >= E) return;
    int s = src[e], d = dst[e];
    nbr_a[atomicAdd(cur_a + d, 1)] = s;   // author's doc neighbors
    nbr_d[atomicAdd(cur_d + s, 1)] = d;   // doc's author neighbors
}

// ================= gather mean-aggregation =================
// one 16-lane group per destination node; lane f owns features [8f, 8f+8)
__global__ __launch_bounds__(256) void agg_mean(
    const u16* __restrict__ x, const int* __restrict__ offs,
    const int* __restrict__ nbr, u16* __restrict__ out, int N) {
    int gid = blockIdx.x * 256 + threadIdx.x;
    int node = gid >> 4, f = gid & 15;
    if (node >= N) return;
    int beg = offs[node], end = offs[node + 1];
    float acc[8] = {0, 0, 0, 0, 0, 0, 0, 0};
    int i = beg;
    for (; i + 1 < end; i += 2) {          // 2-way unroll: 2 gathers in flight
        int s0 = nbr[i], s1 = nbr[i + 1];
        uint4 q0 = *(const uint4*)(x + (size_t)s0 * 128 + f * 8);
        uint4 q1 = *(const uint4*)(x + (size_t)s1 * 128 + f * 8);
        acc[0] += bf2f((u16)(q0.x & 0xffff)) + bf2f((u16)(q1.x & 0xffff));
        acc[1] += bf2f((u16)(q0.x >> 16))    + bf2f((u16)(q1.x >> 16));
        acc[2] += bf2f((u16)(q0.y & 0xffff)) + bf2f((u16)(q1.y & 0xffff));
        acc[3] += bf2f((u16)(q0.y >> 16))    + bf2f((u16)(q1.y >> 16));
        acc[4] += bf2f((u16)(q0.z & 0xffff)) + bf2f((u16)(q1.z & 0xffff));
        acc[5] += bf2f((u16)(q0.z >> 16))    + bf2f((u16)(q1.z >> 16));
        acc[6] += bf2f((u16)(q0.w & 0xffff)) + bf2f((u16)(q1.w & 0xffff));
        acc[7] += bf2f((u16)(q0.w >> 16))    + bf2f((u16)(q1.w >> 16));
    }
    if (i < end) {
        int s0 = nbr[i];
        uint4 q0 = *(const uint4*)(x + (size_t)s0 * 128 + f * 8);
        acc[0] += bf2f((u16)(q0.x & 0xffff));
        acc[1] += bf2f((u16)(q0.x >> 16));
        acc[2] += bf2f((u16)(q0.y & 0xffff));
        acc[3] += bf2f((u16)(q0.y >> 16));
        acc[4] += bf2f((u16)(q0.z & 0xffff));
        acc[5] += bf2f((u16)(q0.z >> 16));
        acc[6] += bf2f((u16)(q0.w & 0xffff));
        acc[7] += bf2f((u16)(q0.w >> 16));
    }
    float inv = 1.0f / fmaxf((float)(end - beg), 1.0f);
    u16 o[8];
#pragma unroll
    for (int j = 0; j < 8; ++j) o[j] = f2bf(acc[j] * inv);
    *(uint4*)(out + (size_t)node * 128 + f * 8) = *(const uint4*)o;
}

// ------------- 128x128 weight transposes f32 -> bf16 (9 mats) -------------
struct TPack { const float* src[9]; u16* dst[9]; };
__global__ __launch_bounds__(256) void transpose_all(TPack p) {
    int mat = blockIdx.y;
    const float* s = p.src[mat];
    u16* d = p.dst[mat];
    int i = blockIdx.x * 256 + threadIdx.x;   // gridDim.x = 64 -> 16384 elems
    int k = i >> 7, n = i & 127;
    d[(size_t)n * 128 + k] = f2bf(s[(size_t)k * 128 + n]);  // WT[n][k] = W[k][n]
}

// ------------- row gather + f32->bf16 (x_author = emb[ids]) ---------------
__global__ __launch_bounds__(256) void gather_rows(
    const float* __restrict__ src, const int* __restrict__ ids,
    u16* __restrict__ out, int N) {
    int gid = blockIdx.x * 256 + threadIdx.x;
    if (gid >= N * 16) return;
    int n = gid >> 4, f = gid & 15;
    int id = ids[n];
    const float* s = src + (size_t)id * 128 + f * 8;
    float4 lo = *(const float4*)(s);
    float4 hi = *(const float4*)(s + 4);
    u16 o[8] = {f2bf(lo.x), f2bf(lo.y), f2bf(lo.z), f2bf(lo.w),
                f2bf(hi.x), f2bf(hi.y), f2bf(hi.z), f2bf(hi.w)};
    *(uint4*)(out + (size_t)n * 128 + f * 8) = *(const uint4*)o;
}

// ---------------- fused SAGE output GEMM ----------------
// out[M,128] = maybe_relu( A1 @ W1 + A2 @ W2 + bias )
// A1: f32 rows (A1f, doc encoder) OR bf16 rows (A1b, pre-normalized agg).
// W*T pre-transposed [n][k] bf16 so B-frags are contiguous 16B loads.
// MFMA 16x16x32 bf16: A[m=lane&15][k=(lane>>4)*8+j]; C/D col=lane&15,
// row=(lane>>4)*4+r  (guide §3, m89/m91-verified).
__global__ __launch_bounds__(256) void sage_gemm(
    const float* __restrict__ A1f, const u16* __restrict__ A1b,
    const u16* __restrict__ W1T,
    const u16* __restrict__ A2b, const u16* __restrict__ W2T,
    const float* __restrict__ bias, const int do_relu,
    u16* __restrict__ out, const int M) {
    const int lane = threadIdx.x & 63;
    const int wave = threadIdx.x >> 6;
    const int m0 = (blockIdx.x * 4 + wave) * 16;   // 16 rows per wave
    if (m0 >= M) return;                            // M % 16 == 0 for all calls
    const int r15 = lane & 15;
    const int kq = lane >> 4;
    const int m = m0 + r15;

    vf32x4 acc[8];
#pragma unroll
    for (int i = 0; i < 8; ++i) acc[i] = (vf32x4)(0.0f);

    if (A1f) {
        const float* arow = A1f + (size_t)m * 128 + kq * 8;
#pragma unroll
        for (int ks = 0; ks < 4; ++ks) {
            const float4 lo = *(const float4*)(arow + ks * 32);
            const float4 hi = *(const float4*)(arow + ks * 32 + 4);
            vbf16x8 a;
            a[0] = (short)f2bf(lo.x); a[1] = (short)f2bf(lo.y);
            a[2] = (short)f2bf(lo.z); a[3] = (short)f2bf(lo.w);
            a[4] = (short)f2bf(hi.x); a[5] = (short)f2bf(hi.y);
            a[6] = (short)f2bf(hi.z); a[7] = (short)f2bf(hi.w);
#pragma unroll
            for (int nt = 0; nt < 8; ++nt) {
                vbf16x8 b = *(const vbf16x8*)(W1T + (size_t)(nt * 16 + r15) * 128 + ks * 32 + kq * 8);
                acc[nt] = __builtin_amdgcn_mfma_f32_16x16x32_bf16(a, b, acc[nt], 0, 0, 0);
            }
        }
    } else {
        const u16* arow = A1b + (size_t)m * 128 + kq * 8;
#pragma unroll
        for (int ks = 0; ks < 4; ++ks) {
            vbf16x8 a = *(const vbf16x8*)(arow + ks * 32);
#pragma unroll
            for (int nt = 0; nt < 8; ++nt) {
                vbf16x8 b = *(const vbf16x8*)(W1T + (size_t)(nt * 16 + r15) * 128 + ks * 32 + kq * 8);
                acc[nt] = __builtin_amdgcn_mfma_f32_16x16x32_bf16(a, b, acc[nt], 0, 0, 0);
            }
        }
    }

    if (A2b) {
        const u16* arow = A2b + (size_t)m * 128 + kq * 8;
#pragma unroll
        for (int ks = 0; ks < 4; ++ks) {
            vbf16x8 a = *(const vbf16x8*)(arow + ks * 32);
#pragma unroll
            for (int nt = 0; nt < 8; ++nt) {
                vbf16x8 b = *(const vbf16x8*)(W2T + (size_t)(nt * 16 + r15) * 128 + ks * 32 + kq * 8);
                acc[nt] = __builtin_amdgcn_mfma_f32_16x16x32_bf16(a, b, acc[nt], 0, 0, 0);
            }
        }
    }

    // epilogue: bias + optional relu, write bf16
#pragma unroll
    for (int nt = 0; nt < 8; ++nt) {
        const float bv = bias ? bias[nt * 16 + r15] : 0.0f;
#pragma unroll
        for (int r = 0; r < 4; ++r) {
            float v = acc[nt][r] + bv;
            if (do_relu) v = fmaxf(v, 0.0f);
            out[(size_t)(m0 + kq * 4 + r) * 128 + nt * 16 + r15] = f2bf(v);
        }
    }
}

// ---------------- edge scorer: pred[e] = dot(od[i0[e]], oa[i1[e]]) --------
__global__ __launch_bounds__(256) void edge_dot(
    const u16* __restrict__ od, const u16* __restrict__ oa,
    const int* __restrict__ i0, const int* __restrict__ i1,
    float* __restrict__ pred, int EL) {
    int gid = blockIdx.x * 256 + threadIdx.x;
    if (gid >= EL * 16) return;
    int e = gid >> 4, f = gid & 15;
    uint4 x = *(const uint4*)(od + (size_t)i0[e] * 128 + f * 8);
    uint4 y = *(const uint4*)(oa + (size_t)i1[e] * 128 + f * 8);
    float s = 0.0f;
    s += bf2f((u16)(x.x & 0xffff)) * bf2f((u16)(y.x & 0xffff));
    s += bf2f((u16)(x.x >> 16))    * bf2f((u16)(y.x >> 16));
    s += bf2f((u16)(x.y & 0xffff)) * bf2f((u16)(y.y & 0xffff));
    s += bf2f((u16)(x.y >> 16))    * bf2f((u16)(y.y >> 16));
    s += bf2f((u16)(x.z & 0xffff)) * bf2f((u16)(y.z & 0xffff));
    s += bf2f((u16)(x.z >> 16))    * bf2f((u16)(y.z >> 16));
    s += bf2f((u16)(x.w & 0xffff)) * bf2f((u16)(y.w & 0xffff));
    s += bf2f((u16)(x.w >> 16))    * bf2f((u16)(y.w >> 16));
    s += __shfl_xor(s, 1);
    s += __shfl_xor(s, 2);
    s += __shfl_xor(s, 4);
    s += __shfl_xor(s, 8);
    if (f == 0) pred[e] = s;
}

extern "C" void kernel_launch(void* const* d_in, const int* in_sizes, int n_in,
                              void* d_out, int out_size, void* d_ws, size_t ws_size,
                              hipStream_t stream) {
    const float* doc_x    = (const float*)d_in[0];
    const int*   auth_id  = (const int*)d_in[1];
    const int*   eidx     = (const int*)d_in[2];
    const int*   elidx    = (const int*)d_in[3];
    const float* W_doc    = (const float*)d_in[4];
    const float* b_doc    = (const float*)d_in[5];
    const float* emb      = (const float*)d_in[6];
    const float* c1_da_Wl = (const float*)d_in[7];
    const float* c1_da_bl = (const float*)d_in[8];
    const float* c1_da_Wr = (const float*)d_in[9];
    const float* c1_ad_Wl = (const float*)d_in[10];
    const float* c1_ad_bl = (const float*)d_in[11];
    const float* c1_ad_Wr = (const float*)d_in[12];
    const float* c2_da_Wl = (const float*)d_in[13];
    const float* c2_da_bl = (const float*)d_in[14];
    const float* c2_da_Wr = (const float*)d_in[15];
    const float* c2_ad_Wl = (const float*)d_in[16];
    const float* c2_ad_bl = (const float*)d_in[17];
    const float* c2_ad_Wr = (const float*)d_in[18];

    const int ND = in_sizes[0] / 128;
    const int NA = in_sizes[1];
    const int E  = in_sizes[2] / 2;
    const int EL = in_sizes[3] / 2;
    const int* e_src = eidx;        // doc endpoints
    const int* e_dst = eidx + E;    // author endpoints
    const int NBD = (ND + 255) / 256, NBA = (NA + 255) / 256;

    // ---- workspace layout ----
    char* base = (char*)d_ws;
    size_t off = 0;
    auto alloc = [&](size_t bytes) {
        void* p = base + off;
        off = (off + bytes + 255) & ~(size_t)255;
        return p;
    };
    u16*  xdoc  = (u16*)alloc((size_t)ND * 128 * 2);   // later reused as o_d
    u16*  xauth = (u16*)alloc((size_t)NA * 128 * 2);   // later reused as o_a
    u16*  hd    = (u16*)alloc((size_t)ND * 128 * 2);
    u16*  ha    = (u16*)alloc((size_t)NA * 128 * 2);
    u16*  aggb  = (u16*)alloc((size_t)ND * 128 * 2);   // shared agg output
    u16*  wt    = (u16*)alloc((size_t)9 * 128 * 128 * 2);
    int*  cnt_d = (int*)alloc((size_t)ND * 4);
    int*  cnt_a = (int*)alloc((size_t)NA * 4);
    int*  incl_d = (int*)alloc((size_t)ND * 4);
    int*  incl_a = (int*)alloc((size_t)NA * 4);
    int*  bs_d  = (int*)alloc((size_t)NBD * 4);
    int*  bs_a  = (int*)alloc((size_t)NBA * 4);
    int*  offs_d = (int*)alloc((size_t)(ND + 1) * 4);
    int*  offs_a = (int*)alloc((size_t)(NA + 1) * 4);
    int*  cur_d = (int*)alloc((size_t)ND * 4);
    int*  cur_a = (int*)alloc((size_t)NA * 4);
    int*  nbr_d = (int*)alloc((size_t)E * 4);
    int*  nbr_a = (int*)alloc((size_t)E * 4);
    (void)ws_size; (void)n_in; (void)out_size;
    u16* od = xdoc;   // layer-2 outputs overwrite layer-0 features
    u16* oa = xauth;

    // ---- CSR build (once; reused by both layers) ----
    hipMemsetAsync(cnt_d, 0, (size_t)ND * 4, stream);
    hipMemsetAsync(cnt_a, 0, (size_t)NA * 4, stream);
    hist_kernel<<<(E + 255) / 256, 256, 0, stream>>>(e_src, e_dst, cnt_d, cnt_a, E);
    scan1<<<NBD, 256, 0, stream>>>(cnt_d, incl_d, bs_d, ND);
    scan1<<<NBA, 256, 0, stream>>>(cnt_a, incl_a, bs_a, NA);
    scan2<<<1, 256, 0, stream>>>(bs_d, NBD);
    scan2<<<1, 256, 0, stream>>>(bs_a, NBA);
    scan3<<<NBD, 256, 0, stream>>>(incl_d, bs_d, offs_d, ND);
    scan3<<<NBA, 256, 0, stream>>>(incl_a, bs_a, offs_a, NA);
    hipMemcpyAsync(cur_d, offs_d, (size_t)ND * 4, hipMemcpyDeviceToDevice, stream);
    hipMemcpyAsync(cur_a, offs_a, (size_t)NA * 4, hipMemcpyDeviceToDevice, stream);
    fill_kernel<<<(E + 255) / 256, 256, 0, stream>>>(
        e_src, e_dst, cur_d, cur_a, nbr_d, nbr_a, E);

    // ---- weight transposes (f32 -> bf16) ----
    TPack tp;
    const float* srcs[9] = {W_doc, c1_da_Wl, c1_da_Wr, c1_ad_Wl, c1_ad_Wr,
                            c2_da_Wl, c2_da_Wr, c2_ad_Wl, c2_ad_Wr};
    for (int i = 0; i < 9; ++i) { tp.src[i] = srcs[i]; tp.dst[i] = wt + (size_t)i * 16384; }
    transpose_all<<<dim3(64, 9), 256, 0, stream>>>(tp);
    const u16 *WTdoc = wt, *WT_c1daL = wt + 16384, *WT_c1daR = wt + 2 * 16384,
              *WT_c1adL = wt + 3 * 16384, *WT_c1adR = wt + 4 * 16384,
              *WT_c2daL = wt + 5 * 16384, *WT_c2daR = wt + 6 * 16384,
              *WT_c2adL = wt + 7 * 16384, *WT_c2adR = wt + 8 * 16384;

    // ---- node features ----
    gather_rows<<<(NA * 16 + 255) / 256, 256, 0, stream>>>(emb, auth_id, xauth, NA);
    sage_gemm<<<(ND + 63) / 64, 256, 0, stream>>>(
        doc_x, nullptr, WTdoc, nullptr, nullptr, b_doc, 0, xdoc, ND);

    // ---- layer 1: doc->author (h_a, relu) ----
    agg_mean<<<(NA * 16 + 255) / 256, 256, 0, stream>>>(xdoc, offs_a, nbr_a, aggb, NA);
    sage_gemm<<<(NA + 63) / 64, 256, 0, stream>>>(
        nullptr, aggb, WT_c1daL, xauth, WT_c1daR, c1_da_bl, 1, ha, NA);

    // ---- layer 1: author->doc (h_d, relu) ----
    agg_mean<<<(ND * 16 + 255) / 256, 256, 0, stream>>>(xauth, offs_d, nbr_d, aggb, ND);
    sage_gemm<<<(ND + 63) / 64, 256, 0, stream>>>(
        nullptr, aggb, WT_c1adL, xdoc, WT_c1adR, c1_ad_bl, 1, hd, ND);

    // ---- layer 2: doc->author (o_a) ----
    agg_mean<<<(NA * 16 + 255) / 256, 256, 0, stream>>>(hd, offs_a, nbr_a, aggb, NA);
    sage_gemm<<<(NA + 63) / 64, 256, 0, stream>>>(
        nullptr, aggb, WT_c2daL, ha, WT_c2daR, c2_da_bl, 0, oa, NA);

    // ---- layer 2: author->doc (o_d) ----
    agg_mean<<<(ND * 16 + 255) / 256, 256, 0, stream>>>(ha, offs_d, nbr_d, aggb, ND);
    sage_gemm<<<(ND + 63) / 64, 256, 0, stream>>>(
        nullptr, aggb, WT_c2adL, hd, WT_c2adR, c2_ad_bl, 0, od, ND);

    // ---- edge scorer ----
    edge_dot<<<(EL * 16 + 255) / 256, 256, 0, stream>>>(
        od, oa, elidx, elidx + EL, (float*)d_out, EL);
}

// Round 4
// 507.432 us; speedup vs baseline: 14.7001x; 1.1994x over previous
//
#include <hip/hip_runtime.h>

typedef unsigned short u16;
typedef __attribute__((ext_vector_type(8))) short vbf16x8;   // 8 bf16 (4 VGPRs)
typedef __attribute__((ext_vector_type(4))) float vf32x4;    // MFMA acc frag

__device__ __forceinline__ float bf2f(u16 u) {
    union { unsigned int i; float f; } v; v.i = ((unsigned int)u) << 16; return v.f;
}
__device__ __forceinline__ u16 f2bf(float f) {
    union { float f; unsigned int i; } v; v.f = f;
    return (u16)((v.i + 0x7fffu + ((v.i >> 16) & 1u)) >> 16);  // RNE
}

// ================= CSR build =================
__global__ __launch_bounds__(256) void hist_kernel(
    const int* __restrict__ src, const int* __restrict__ dst,
    int* __restrict__ cnt_d, int* __restrict__ cnt_a, int E) {
    int e = blockIdx.x * 256 + threadIdx.x;
    if (e >= E) return;
    atomicAdd(cnt_d + src[e], 1);
    atomicAdd(cnt_a + dst[e], 1);
}

// inclusive scan within 256-blocks + block sums
__global__ __launch_bounds__(256) void scan1(
    const int* __restrict__ in, int* __restrict__ incl,
    int* __restrict__ bsums, int N) {
    __shared__ int sh[256];
    int tid = threadIdx.x, gid = blockIdx.x * 256 + tid;
    int v = gid < N ? in[gid] : 0;
    sh[tid] = v; __syncthreads();
    for (int off = 1; off < 256; off <<= 1) {
        int t = tid >= off ? sh[tid - off] : 0; __syncthreads();
        sh[tid] += t; __syncthreads();
    }
    if (gid < N) incl[gid] = sh[tid];
    if (tid == 255) bsums[blockIdx.x] = sh[255];
}

// single-block exclusive scan of block sums
__global__ __launch_bounds__(256) void scan2(int* __restrict__ bs, int nb) {
    __shared__ int sh[256];
    __shared__ int carry;
    int tid = threadIdx.x;
    if (tid == 0) carry = 0;
    __syncthreads();
    for (int base = 0; base < nb; base += 256) {
        int i = base + tid;
        int v = i < nb ? bs[i] : 0;
        sh[tid] = v; __syncthreads();
        for (int off = 1; off < 256; off <<= 1) {
            int t = tid >= off ? sh[tid - off] : 0; __syncthreads();
            sh[tid] += t; __syncthreads();
        }
        if (i < nb) bs[i] = carry + sh[tid] - v;   // exclusive
        __syncthreads();
        if (tid == 255) carry += sh[255];
        __syncthreads();
    }
}

// offsets[i+1] = incl[i] + block_offset ; offsets[0] = 0
__global__ __launch_bounds__(256) void scan3(
    const int* __restrict__ incl, const int* __restrict__ bsoff,
    int* __restrict__ offs, int N) {
    int gid = blockIdx.x * 256 + threadIdx.x;
    if (gid < N) offs[gid + 1] = incl[gid] + bsoff[blockIdx.x];
    if (gid == 0) offs[0] = 0;
}

// place each edge into both adjacency lists via atomic cursors
__global__ __launch_bounds__(256) void fill_kernel(
    const int* __restrict__ src, const int* __restrict__ dst,
    int* __restrict__ cur_d, int* __restrict__ cur_a,
    int* __restrict__ nbr_d, int* __restrict__ nbr_a, int E) {
    int e = blockIdx.x * 256 + threadIdx.x;
    if (e >= E) return;
    int s = src[e], d = dst[e];
    nbr_a[atomicAdd(cur_a + d, 1)] = s;   // author's doc neighbors
    nbr_d[atomicAdd(cur_d + s, 1)] = d;   // doc's author neighbors
}

// ================= gather mean-aggregation =================
// one 16-lane group per destination node; lane f owns features [8f, 8f+8)
__global__ __launch_bounds__(256) void agg_mean(
    const u16* __restrict__ x, const int* __restrict__ offs,
    const int* __restrict__ nbr, u16* __restrict__ out, int N) {
    int gid = blockIdx.x * 256 + threadIdx.x;
    int node = gid >> 4, f = gid & 15;
    if (node >= N) return;
    int beg = offs[node], end = offs[node + 1];
    float acc[8] = {0, 0, 0, 0, 0, 0, 0, 0};
    int i = beg;
    for (; i + 1 < end; i += 2) {          // 2-way unroll: 2 gathers in flight
        int s0 = nbr[i], s1 = nbr[i + 1];
        uint4 q0 = *(const uint4*)(x + (size_t)s0 * 128 + f * 8);
        uint4 q1 = *(const uint4*)(x + (size_t)s1 * 128 + f * 8);
        acc[0] += bf2f((u16)(q0.x & 0xffff)) + bf2f((u16)(q1.x & 0xffff));
        acc[1] += bf2f((u16)(q0.x >> 16))    + bf2f((u16)(q1.x >> 16));
        acc[2] += bf2f((u16)(q0.y & 0xffff)) + bf2f((u16)(q1.y & 0xffff));
        acc[3] += bf2f((u16)(q0.y >> 16))    + bf2f((u16)(q1.y >> 16));
        acc[4] += bf2f((u16)(q0.z & 0xffff)) + bf2f((u16)(q1.z & 0xffff));
        acc[5] += bf2f((u16)(q0.z >> 16))    + bf2f((u16)(q1.z >> 16));
        acc[6] += bf2f((u16)(q0.w & 0xffff)) + bf2f((u16)(q1.w & 0xffff));
        acc[7] += bf2f((u16)(q0.w >> 16))    + bf2f((u16)(q1.w >> 16));
    }
    if (i < end) {
        int s0 = nbr[i];
        uint4 q0 = *(const uint4*)(x + (size_t)s0 * 128 + f * 8);
        acc[0] += bf2f((u16)(q0.x & 0xffff));
        acc[1] += bf2f((u16)(q0.x >> 16));
        acc[2] += bf2f((u16)(q0.y & 0xffff));
        acc[3] += bf2f((u16)(q0.y >> 16));
        acc[4] += bf2f((u16)(q0.z & 0xffff));
        acc[5] += bf2f((u16)(q0.z >> 16));
        acc[6] += bf2f((u16)(q0.w & 0xffff));
        acc[7] += bf2f((u16)(q0.w >> 16));
    }
    float inv = 1.0f / fmaxf((float)(end - beg), 1.0f);
    u16 o[8];
#pragma unroll
    for (int j = 0; j < 8; ++j) o[j] = f2bf(acc[j] * inv);
    *(uint4*)(out + (size_t)node * 128 + f * 8) = *(const uint4*)o;
}

// ------------- 128x128 weight transposes f32 -> bf16 (9 mats) -------------
struct TPack { const float* src[9]; u16* dst[9]; };
__global__ __launch_bounds__(256) void transpose_all(TPack p) {
    int mat = blockIdx.y;
    const float* s = p.src[mat];
    u16* d = p.dst[mat];
    int i = blockIdx.x * 256 + threadIdx.x;   // gridDim.x = 64 -> 16384 elems
    int k = i >> 7, n = i & 127;
    d[(size_t)n * 128 + k] = f2bf(s[(size_t)k * 128 + n]);  // WT[n][k] = W[k][n]
}

// ------------- row gather + f32->bf16 (x_author = emb[ids]) ---------------
__global__ __launch_bounds__(256) void gather_rows(
    const float* __restrict__ src, const int* __restrict__ ids,
    u16* __restrict__ out, int N) {
    int gid = blockIdx.x * 256 + threadIdx.x;
    if (gid >= N * 16) return;
    int n = gid >> 4, f = gid & 15;
    int id = ids[n];
    const float* s = src + (size_t)id * 128 + f * 8;
    float4 lo = *(const float4*)(s);
    float4 hi = *(const float4*)(s + 4);
    u16 o[8] = {f2bf(lo.x), f2bf(lo.y), f2bf(lo.z), f2bf(lo.w),
                f2bf(hi.x), f2bf(hi.y), f2bf(hi.z), f2bf(hi.w)};
    *(uint4*)(out + (size_t)n * 128 + f * 8) = *(const uint4*)o;
}

// ---------------- fused SAGE output GEMM (LDS-staged weights) -------------
// out[M,128] = maybe_relu( A1 @ W1 + A2 @ W2 + bias )
// A1: f32 rows (A1f, doc encoder) OR bf16 rows (A1b). A2 optional.
// Block = 128 rows, 4 waves; each wave 32 rows (two 16-row A-frags sharing
// every B-frag -> 2 MFMA per ds_read_b128). Active weight matrix staged in
// 32 KB LDS with 16B-block XOR swizzle (pos = bk ^ (n&15)) so B-frag reads
// spread over all bank groups (naive layout = 16-way conflict).
// MFMA 16x16x32 bf16: A[m=lane&15][k=(lane>>4)*8+j]; C/D col=lane&15,
// row=(lane>>4)*4+r  (guide §3, m89/m91-verified).
__global__ __launch_bounds__(256) void sage_gemm(
    const float* __restrict__ A1f, const u16* __restrict__ A1b,
    const u16* __restrict__ W1T,
    const u16* __restrict__ A2b, const u16* __restrict__ W2T,
    const float* __restrict__ bias, const int do_relu,
    u16* __restrict__ out, const int M) {
    __shared__ u16 WS[128 * 128];   // 32 KB
    const int tid = threadIdx.x;
    const int lane = tid & 63, wave = tid >> 6;
    const int r15 = lane & 15, kq = lane >> 4;
    const int rowbase = blockIdx.x * 128 + wave * 32;
    const int m0 = rowbase + r15;          // frag0 rows
    const int m1 = rowbase + 16 + r15;     // frag1 rows
    const bool v0 = rowbase < M;           // M % 16 == 0 always
    const bool v1 = rowbase + 16 < M;

    vf32x4 acc0[8], acc1[8];
#pragma unroll
    for (int i = 0; i < 8; ++i) { acc0[i] = (vf32x4)(0.0f); acc1[i] = (vf32x4)(0.0f); }

    const int nmats = A2b ? 2 : 1;
    for (int mat = 0; mat < nmats; ++mat) {
        const u16* WT = mat ? W2T : W1T;
        if (mat) __syncthreads();          // protect WS before overwrite
        // stage 32 KB: 2048 16B-blocks; thread t block L, coalesced global read
#pragma unroll
        for (int i = 0; i < 8; ++i) {
            int L = i * 256 + tid;
            int n = L >> 4, bk = L & 15;
            uint4 v = *(const uint4*)(WT + (size_t)L * 8);
            *(uint4*)(WS + ((size_t)n * 16 + (bk ^ (n & 15))) * 8) = v;
        }
        __syncthreads();

        const u16* Ab = mat ? A2b : A1b;
        const bool f32path = (mat == 0) && (A1f != nullptr);
#pragma unroll
        for (int ks = 0; ks < 4; ++ks) {
            vbf16x8 a0 = (vbf16x8)(short)0, a1 = (vbf16x8)(short)0;
            if (f32path) {
                if (v0) {
                    const float* p = A1f + (size_t)m0 * 128 + ks * 32 + kq * 8;
                    float4 lo = *(const float4*)p, hi = *(const float4*)(p + 4);
                    a0[0] = (short)f2bf(lo.x); a0[1] = (short)f2bf(lo.y);
                    a0[2] = (short)f2bf(lo.z); a0[3] = (short)f2bf(lo.w);
                    a0[4] = (short)f2bf(hi.x); a0[5] = (short)f2bf(hi.y);
                    a0[6] = (short)f2bf(hi.z); a0[7] = (short)f2bf(hi.w);
                }
                if (v1) {
                    const float* p = A1f + (size_t)m1 * 128 + ks * 32 + kq * 8;
                    float4 lo = *(const float4*)p, hi = *(const float4*)(p + 4);
                    a1[0] = (short)f2bf(lo.x); a1[1] = (short)f2bf(lo.y);
                    a1[2] = (short)f2bf(lo.z); a1[3] = (short)f2bf(lo.w);
                    a1[4] = (short)f2bf(hi.x); a1[5] = (short)f2bf(hi.y);
                    a1[6] = (short)f2bf(hi.z); a1[7] = (short)f2bf(hi.w);
                }
            } else {
                if (v0) a0 = *(const vbf16x8*)(Ab + (size_t)m0 * 128 + ks * 32 + kq * 8);
                if (v1) a1 = *(const vbf16x8*)(Ab + (size_t)m1 * 128 + ks * 32 + kq * 8);
            }
#pragma unroll
            for (int nt = 0; nt < 8; ++nt) {
                vbf16x8 b = *(const vbf16x8*)(
                    WS + ((size_t)(nt * 16 + r15) * 16 + ((ks * 4 + kq) ^ r15)) * 8);
                acc0[nt] = __builtin_amdgcn_mfma_f32_16x16x32_bf16(a0, b, acc0[nt], 0, 0, 0);
                acc1[nt] = __builtin_amdgcn_mfma_f32_16x16x32_bf16(a1, b, acc1[nt], 0, 0, 0);
            }
        }
    }

    // epilogue: bias + optional relu, write bf16
#pragma unroll
    for (int nt = 0; nt < 8; ++nt) {
        const float bv = bias ? bias[nt * 16 + r15] : 0.0f;
#pragma unroll
        for (int r = 0; r < 4; ++r) {
            if (v0) {
                float v = acc0[nt][r] + bv;
                if (do_relu) v = fmaxf(v, 0.0f);
                out[(size_t)(rowbase + kq * 4 + r) * 128 + nt * 16 + r15] = f2bf(v);
            }
            if (v1) {
                float v = acc1[nt][r] + bv;
                if (do_relu) v = fmaxf(v, 0.0f);
                out[(size_t)(rowbase + 16 + kq * 4 + r) * 128 + nt * 16 + r15] = f2bf(v);
            }
        }
    }
}

// ---------------- edge scorer: pred[e] = dot(od[i0[e]], oa[i1[e]]) --------
__global__ __launch_bounds__(256) void edge_dot(
    const u16* __restrict__ od, const u16* __restrict__ oa,
    const int* __restrict__ i0, const int* __restrict__ i1,
    float* __restrict__ pred, int EL) {
    int gid = blockIdx.x * 256 + threadIdx.x;
    if (gid >= EL * 16) return;
    int e = gid >> 4, f = gid & 15;
    uint4 x = *(const uint4*)(od + (size_t)i0[e] * 128 + f * 8);
    uint4 y = *(const uint4*)(oa + (size_t)i1[e] * 128 + f * 8);
    float s = 0.0f;
    s += bf2f((u16)(x.x & 0xffff)) * bf2f((u16)(y.x & 0xffff));
    s += bf2f((u16)(x.x >> 16))    * bf2f((u16)(y.x >> 16));
    s += bf2f((u16)(x.y & 0xffff)) * bf2f((u16)(y.y & 0xffff));
    s += bf2f((u16)(x.y >> 16))    * bf2f((u16)(y.y >> 16));
    s += bf2f((u16)(x.z & 0xffff)) * bf2f((u16)(y.z & 0xffff));
    s += bf2f((u16)(x.z >> 16))    * bf2f((u16)(y.z >> 16));
    s += bf2f((u16)(x.w & 0xffff)) * bf2f((u16)(y.w & 0xffff));
    s += bf2f((u16)(x.w >> 16))    * bf2f((u16)(y.w >> 16));
    s += __shfl_xor(s, 1);
    s += __shfl_xor(s, 2);
    s += __shfl_xor(s, 4);
    s += __shfl_xor(s, 8);
    if (f == 0) pred[e] = s;
}

extern "C" void kernel_launch(void* const* d_in, const int* in_sizes, int n_in,
                              void* d_out, int out_size, void* d_ws, size_t ws_size,
                              hipStream_t stream) {
    const float* doc_x    = (const float*)d_in[0];
    const int*   auth_id  = (const int*)d_in[1];
    const int*   eidx     = (const int*)d_in[2];
    const int*   elidx    = (const int*)d_in[3];
    const float* W_doc    = (const float*)d_in[4];
    const float* b_doc    = (const float*)d_in[5];
    const float* emb      = (const float*)d_in[6];
    const float* c1_da_Wl = (const float*)d_in[7];
    const float* c1_da_bl = (const float*)d_in[8];
    const float* c1_da_Wr = (const float*)d_in[9];
    const float* c1_ad_Wl = (const float*)d_in[10];
    const float* c1_ad_bl = (const float*)d_in[11];
    const float* c1_ad_Wr = (const float*)d_in[12];
    const float* c2_da_Wl = (const float*)d_in[13];
    const float* c2_da_bl = (const float*)d_in[14];
    const float* c2_da_Wr = (const float*)d_in[15];
    const float* c2_ad_Wl = (const float*)d_in[16];
    const float* c2_ad_bl = (const float*)d_in[17];
    const float* c2_ad_Wr = (const float*)d_in[18];

    const int ND = in_sizes[0] / 128;
    const int NA = in_sizes[1];
    const int E  = in_sizes[2] / 2;
    const int EL = in_sizes[3] / 2;
    const int* e_src = eidx;        // doc endpoints
    const int* e_dst = eidx + E;    // author endpoints
    const int NBD = (ND + 255) / 256, NBA = (NA + 255) / 256;

    // ---- workspace layout ----
    char* base = (char*)d_ws;
    size_t off = 0;
    auto alloc = [&](size_t bytes) {
        void* p = base + off;
        off = (off + bytes + 255) & ~(size_t)255;
        return p;
    };
    u16*  xdoc  = (u16*)alloc((size_t)ND * 128 * 2);   // later reused as o_d
    u16*  xauth = (u16*)alloc((size_t)NA * 128 * 2);   // later reused as o_a
    u16*  hd    = (u16*)alloc((size_t)ND * 128 * 2);
    u16*  ha    = (u16*)alloc((size_t)NA * 128 * 2);
    u16*  aggb  = (u16*)alloc((size_t)ND * 128 * 2);   // shared agg output
    u16*  wt    = (u16*)alloc((size_t)9 * 128 * 128 * 2);
    int*  cnt_d = (int*)alloc((size_t)ND * 4);
    int*  cnt_a = (int*)alloc((size_t)NA * 4);
    int*  incl_d = (int*)alloc((size_t)ND * 4);
    int*  incl_a = (int*)alloc((size_t)NA * 4);
    int*  bs_d  = (int*)alloc((size_t)NBD * 4);
    int*  bs_a  = (int*)alloc((size_t)NBA * 4);
    int*  offs_d = (int*)alloc((size_t)(ND + 1) * 4);
    int*  offs_a = (int*)alloc((size_t)(NA + 1) * 4);
    int*  cur_d = (int*)alloc((size_t)ND * 4);
    int*  cur_a = (int*)alloc((size_t)NA * 4);
    int*  nbr_d = (int*)alloc((size_t)E * 4);
    int*  nbr_a = (int*)alloc((size_t)E * 4);
    (void)ws_size; (void)n_in; (void)out_size;
    u16* od = xdoc;   // layer-2 outputs overwrite layer-0 features
    u16* oa = xauth;

    // ---- CSR build (once; reused by both layers) ----
    hipMemsetAsync(cnt_d, 0, (size_t)ND * 4, stream);
    hipMemsetAsync(cnt_a, 0, (size_t)NA * 4, stream);
    hist_kernel<<<(E + 255) / 256, 256, 0, stream>>>(e_src, e_dst, cnt_d, cnt_a, E);
    scan1<<<NBD, 256, 0, stream>>>(cnt_d, incl_d, bs_d, ND);
    scan1<<<NBA, 256, 0, stream>>>(cnt_a, incl_a, bs_a, NA);
    scan2<<<1, 256, 0, stream>>>(bs_d, NBD);
    scan2<<<1, 256, 0, stream>>>(bs_a, NBA);
    scan3<<<NBD, 256, 0, stream>>>(incl_d, bs_d, offs_d, ND);
    scan3<<<NBA, 256, 0, stream>>>(incl_a, bs_a, offs_a, NA);
    hipMemcpyAsync(cur_d, offs_d, (size_t)ND * 4, hipMemcpyDeviceToDevice, stream);
    hipMemcpyAsync(cur_a, offs_a, (size_t)NA * 4, hipMemcpyDeviceToDevice, stream);
    fill_kernel<<<(E + 255) / 256, 256, 0, stream>>>(
        e_src, e_dst, cur_d, cur_a, nbr_d, nbr_a, E);

    // ---- weight transposes (f32 -> bf16) ----
    TPack tp;
    const float* srcs[9] = {W_doc, c1_da_Wl, c1_da_Wr, c1_ad_Wl, c1_ad_Wr,
                            c2_da_Wl, c2_da_Wr, c2_ad_Wl, c2_ad_Wr};
    for (int i = 0; i < 9; ++i) { tp.src[i] = srcs[i]; tp.dst[i] = wt + (size_t)i * 16384; }
    transpose_all<<<dim3(64, 9), 256, 0, stream>>>(tp);
    const u16 *WTdoc = wt, *WT_c1daL = wt + 16384, *WT_c1daR = wt + 2 * 16384,
              *WT_c1adL = wt + 3 * 16384, *WT_c1adR = wt + 4 * 16384,
              *WT_c2daL = wt + 5 * 16384, *WT_c2daR = wt + 6 * 16384,
              *WT_c2adL = wt + 7 * 16384, *WT_c2adR = wt + 8 * 16384;

    // ---- node features ----
    gather_rows<<<(NA * 16 + 255) / 256, 256, 0, stream>>>(emb, auth_id, xauth, NA);
    sage_gemm<<<(ND + 127) / 128, 256, 0, stream>>>(
        doc_x, nullptr, WTdoc, nullptr, nullptr, b_doc, 0, xdoc, ND);

    // ---- layer 1: doc->author (h_a, relu) ----
    agg_mean<<<(NA * 16 + 255) / 256, 256, 0, stream>>>(xdoc, offs_a, nbr_a, aggb, NA);
    sage_gemm<<<(NA + 127) / 128, 256, 0, stream>>>(
        nullptr, aggb, WT_c1daL, xauth, WT_c1daR, c1_da_bl, 1, ha, NA);

    // ---- layer 1: author->doc (h_d, relu) ----
    agg_mean<<<(ND * 16 + 255) / 256, 256, 0, stream>>>(xauth, offs_d, nbr_d, aggb, ND);
    sage_gemm<<<(ND + 127) / 128, 256, 0, stream>>>(
        nullptr, aggb, WT_c1adL, xdoc, WT_c1adR, c1_ad_bl, 1, hd, ND);

    // ---- layer 2: doc->author (o_a) ----
    agg_mean<<<(NA * 16 + 255) / 256, 256, 0, stream>>>(hd, offs_a, nbr_a, aggb, NA);
    sage_gemm<<<(NA + 127) / 128, 256, 0, stream>>>(
        nullptr, aggb, WT_c2daL, ha, WT_c2daR, c2_da_bl, 0, oa, NA);

    // ---- layer 2: author->doc (o_d) ----
    agg_mean<<<(ND * 16 + 255) / 256, 256, 0, stream>>>(ha, offs_d, nbr_d, aggb, ND);
    sage_gemm<<<(ND + 127) / 128, 256, 0, stream>>>(
        nullptr, aggb, WT_c2adL, hd, WT_c2adR, c2_ad_bl, 0, od, ND);

    // ---- edge scorer ----
    edge_dot<<<(EL * 16 + 255) / 256, 256, 0, stream>>>(
        od, oa, elidx, elidx + EL, (float*)d_out, EL);
}

// Round 5
// 457.644 us; speedup vs baseline: 16.2993x; 1.1088x over previous
//
#include <hip/hip_runtime.h>

typedef unsigned short u16;
typedef __attribute__((ext_vector_type(8))) short vbf16x8;   // 8 bf16 (4 VGPRs)
typedef __attribute__((ext_vector_type(4))) float vf32x4;    // MFMA acc frag

__device__ __forceinline__ float bf2f(u16 u) {
    union { unsigned int i; float f; } v; v.i = ((unsigned int)u) << 16; return v.f;
}
__device__ __forceinline__ u16 f2bf(float f) {
    union { float f; unsigned int i; } v; v.f = f;
    return (u16)((v.i + 0x7fffu + ((v.i >> 16) & 1u)) >> 16);  // RNE
}

// ================= CSR build =================
// cnt = [cnt_d(ND) | cnt_a(NA)] contiguous
__global__ __launch_bounds__(256) void hist_kernel(
    const int* __restrict__ src, const int* __restrict__ dst,
    int* __restrict__ cnt, int ND, int E) {
    int e = blockIdx.x * 256 + threadIdx.x;
    if (e >= E) return;
    atomicAdd(cnt + src[e], 1);
    atomicAdd(cnt + ND + dst[e], 1);
}

// batched inclusive scan within 256-blocks + block sums (d then a segment)
__global__ __launch_bounds__(256) void scan1b(
    const int* __restrict__ cnt, int* __restrict__ incl,
    int* __restrict__ bs, int ND, int NA, int NBD) {
    __shared__ int sh[256];
    int b = blockIdx.x, tid = threadIdx.x;
    const int* in; int* out; int N; int lb;
    if (b < NBD) { in = cnt;      out = incl;      N = ND; lb = b; }
    else         { in = cnt + ND; out = incl + ND; N = NA; lb = b - NBD; }
    int gid = lb * 256 + tid;
    int v = gid < N ? in[gid] : 0;
    sh[tid] = v; __syncthreads();
    for (int off = 1; off < 256; off <<= 1) {
        int t = tid >= off ? sh[tid - off] : 0; __syncthreads();
        sh[tid] += t; __syncthreads();
    }
    if (gid < N) out[gid] = sh[tid];
    if (tid == 255) bs[b] = sh[255];
}

// single-block exclusive scan of block sums, both segments
__global__ __launch_bounds__(256) void scan2b(int* __restrict__ bs, int NBD, int NBA) {
    __shared__ int sh[256];
    __shared__ int carry;
    int tid = threadIdx.x;
    for (int seg = 0; seg < 2; ++seg) {
        int* p = seg ? bs + NBD : bs;
        int nb = seg ? NBA : NBD;
        if (tid == 0) carry = 0;
        __syncthreads();
        for (int base = 0; base < nb; base += 256) {
            int i = base + tid;
            int v = i < nb ? p[i] : 0;
            sh[tid] = v; __syncthreads();
            for (int off = 1; off < 256; off <<= 1) {
                int t = tid >= off ? sh[tid - off] : 0; __syncthreads();
                sh[tid] += t; __syncthreads();
            }
            if (i < nb) p[i] = carry + sh[tid] - v;   // exclusive
            __syncthreads();
            if (tid == 255) carry += sh[255];
            __syncthreads();
        }
    }
}

// offs[gid+1] = incl[gid] + block_offset ; offs[0] = 0 (both sides)
__global__ __launch_bounds__(256) void scan3b(
    const int* __restrict__ incl, const int* __restrict__ bs,
    int* __restrict__ offs_d, int* __restrict__ offs_a,
    int ND, int NA, int NBD) {
    int b = blockIdx.x, tid = threadIdx.x;
    if (b < NBD) {
        int gid = b * 256 + tid;
        if (gid < ND) offs_d[gid + 1] = incl[gid] + bs[b];
        if (gid == 0) offs_d[0] = 0;
    } else {
        int gid = (b - NBD) * 256 + tid;
        if (gid < NA) offs_a[gid + 1] = incl[ND + gid] + bs[b];
        if (gid == 0) offs_a[0] = 0;
    }
}

// place each edge into both adjacency lists; cnt doubles as insertion cursor
// (order within a segment is arbitrary — mean aggregation is order-invariant)
__global__ __launch_bounds__(256) void fill_kernel(
    const int* __restrict__ src, const int* __restrict__ dst,
    int* __restrict__ cnt, const int* __restrict__ offs_d,
    const int* __restrict__ offs_a,
    int* __restrict__ nbr_d, int* __restrict__ nbr_a, int ND, int E) {
    int e = blockIdx.x * 256 + threadIdx.x;
    if (e >= E) return;
    int s = src[e], d = dst[e];
    int pd = offs_d[s] + atomicSub(cnt + s, 1) - 1;
    nbr_d[pd] = d;                       // doc's author neighbors
    int pa = offs_a[d] + atomicSub(cnt + ND + d, 1) - 1;
    nbr_a[pa] = s;                       // author's doc neighbors
}

// ================= fused gather mean-aggregation (both sides) =============
// nodes [0,NA) aggregate docs->author; [NA, NA+ND) aggregate authors->doc
__global__ __launch_bounds__(256) void agg_mean2(
    const u16* __restrict__ xa, const int* __restrict__ offs_a,
    const int* __restrict__ nbr_a, u16* __restrict__ outa, int NA,
    const u16* __restrict__ xd, const int* __restrict__ offs_d,
    const int* __restrict__ nbr_d, u16* __restrict__ outd, int ND) {
    int gid = blockIdx.x * 256 + threadIdx.x;
    int node = gid >> 4, f = gid & 15;
    const u16* x; const int* offs; const int* nbr; u16* out;
    if (node < NA) { x = xa; offs = offs_a; nbr = nbr_a; out = outa; }
    else {
        node -= NA;
        if (node >= ND) return;
        x = xd; offs = offs_d; nbr = nbr_d; out = outd;
    }
    int beg = offs[node], end = offs[node + 1];
    float acc[8] = {0, 0, 0, 0, 0, 0, 0, 0};
    int i = beg;
    for (; i + 1 < end; i += 2) {          // 2-way unroll: 2 gathers in flight
        int s0 = nbr[i], s1 = nbr[i + 1];
        uint4 q0 = *(const uint4*)(x + (size_t)s0 * 128 + f * 8);
        uint4 q1 = *(const uint4*)(x + (size_t)s1 * 128 + f * 8);
        acc[0] += bf2f((u16)(q0.x & 0xffff)) + bf2f((u16)(q1.x & 0xffff));
        acc[1] += bf2f((u16)(q0.x >> 16))    + bf2f((u16)(q1.x >> 16));
        acc[2] += bf2f((u16)(q0.y & 0xffff)) + bf2f((u16)(q1.y & 0xffff));
        acc[3] += bf2f((u16)(q0.y >> 16))    + bf2f((u16)(q1.y >> 16));
        acc[4] += bf2f((u16)(q0.z & 0xffff)) + bf2f((u16)(q1.z & 0xffff));
        acc[5] += bf2f((u16)(q0.z >> 16))    + bf2f((u16)(q1.z >> 16));
        acc[6] += bf2f((u16)(q0.w & 0xffff)) + bf2f((u16)(q1.w & 0xffff));
        acc[7] += bf2f((u16)(q0.w >> 16))    + bf2f((u16)(q1.w >> 16));
    }
    if (i < end) {
        int s0 = nbr[i];
        uint4 q0 = *(const uint4*)(x + (size_t)s0 * 128 + f * 8);
        acc[0] += bf2f((u16)(q0.x & 0xffff));
        acc[1] += bf2f((u16)(q0.x >> 16));
        acc[2] += bf2f((u16)(q0.y & 0xffff));
        acc[3] += bf2f((u16)(q0.y >> 16));
        acc[4] += bf2f((u16)(q0.z & 0xffff));
        acc[5] += bf2f((u16)(q0.z >> 16));
        acc[6] += bf2f((u16)(q0.w & 0xffff));
        acc[7] += bf2f((u16)(q0.w >> 16));
    }
    float inv = 1.0f / fmaxf((float)(end - beg), 1.0f);
    u16 o[8];
#pragma unroll
    for (int j = 0; j < 8; ++j) o[j] = f2bf(acc[j] * inv);
    *(uint4*)(out + (size_t)node * 128 + f * 8) = *(const uint4*)o;
}

// ------ prep: 9 weight transposes (f32->bf16) + author row gather --------
struct TPack { const float* src[9]; u16* dst[9]; };
__global__ __launch_bounds__(256) void prep_kernel(
    TPack p, const float* __restrict__ emb, const int* __restrict__ ids,
    u16* __restrict__ xauth, int NA) {
    int b = blockIdx.x;
    if (b < 576) {                         // 9 mats x 64 blocks
        int mat = b / 64;
        const float* s = p.src[mat];
        u16* d = p.dst[mat];
        int i = (b % 64) * 256 + threadIdx.x;
        int k = i >> 7, n = i & 127;
        d[(size_t)n * 128 + k] = f2bf(s[(size_t)k * 128 + n]);
    } else {
        int gid = (b - 576) * 256 + threadIdx.x;
        if (gid >= NA * 16) return;
        int n = gid >> 4, f = gid & 15;
        int id = ids[n];
        const float* s = emb + (size_t)id * 128 + f * 8;
        float4 lo = *(const float4*)(s);
        float4 hi = *(const float4*)(s + 4);
        u16 o[8] = {f2bf(lo.x), f2bf(lo.y), f2bf(lo.z), f2bf(lo.w),
                    f2bf(hi.x), f2bf(hi.y), f2bf(hi.z), f2bf(hi.w)};
        *(uint4*)(xauth + (size_t)n * 128 + f * 8) = *(const uint4*)o;
    }
}

// ---------------- doc encoder GEMM (f32 A, LDS-staged weights) ------------
// out[M,128] = A1f @ W1T^T + bias. Same tiling as conv_gemm2.
__global__ __launch_bounds__(256) void doc_gemm(
    const float* __restrict__ A1f, const u16* __restrict__ W1T,
    const float* __restrict__ bias, u16* __restrict__ out, const int M) {
    __shared__ u16 WS[128 * 128];   // 32 KB
    const int tid = threadIdx.x;
    const int lane = tid & 63, wave = tid >> 6;
    const int r15 = lane & 15, kq = lane >> 4;
    const int rowbase = blockIdx.x * 128 + wave * 32;
    const int m0 = rowbase + r15, m1 = rowbase + 16 + r15;
    const bool v0 = rowbase < M, v1 = rowbase + 16 < M;

    vf32x4 acc0[8], acc1[8];
#pragma unroll
    for (int i = 0; i < 8; ++i) { acc0[i] = (vf32x4)(0.0f); acc1[i] = (vf32x4)(0.0f); }

#pragma unroll
    for (int i = 0; i < 8; ++i) {
        int L = i * 256 + tid;
        int n = L >> 4, bk = L & 15;
        uint4 v = *(const uint4*)(W1T + (size_t)L * 8);
        *(uint4*)(WS + ((size_t)n * 16 + (bk ^ (n & 15))) * 8) = v;
    }
    __syncthreads();

#pragma unroll
    for (int ks = 0; ks < 4; ++ks) {
        vbf16x8 a0 = (vbf16x8)(short)0, a1 = (vbf16x8)(short)0;
        if (v0) {
            const float* p = A1f + (size_t)m0 * 128 + ks * 32 + kq * 8;
            float4 lo = *(const float4*)p, hi = *(const float4*)(p + 4);
            a0[0] = (short)f2bf(lo.x); a0[1] = (short)f2bf(lo.y);
            a0[2] = (short)f2bf(lo.z); a0[3] = (short)f2bf(lo.w);
            a0[4] = (short)f2bf(hi.x); a0[5] = (short)f2bf(hi.y);
            a0[6] = (short)f2bf(hi.z); a0[7] = (short)f2bf(hi.w);
        }
        if (v1) {
            const float* p = A1f + (size_t)m1 * 128 + ks * 32 + kq * 8;
            float4 lo = *(const float4*)p, hi = *(const float4*)(p + 4);
            a1[0] = (short)f2bf(lo.x); a1[1] = (short)f2bf(lo.y);
            a1[2] = (short)f2bf(lo.z); a1[3] = (short)f2bf(lo.w);
            a1[4] = (short)f2bf(hi.x); a1[5] = (short)f2bf(hi.y);
            a1[6] = (short)f2bf(hi.z); a1[7] = (short)f2bf(hi.w);
        }
#pragma unroll
        for (int nt = 0; nt < 8; ++nt) {
            vbf16x8 b = *(const vbf16x8*)(
                WS + ((size_t)(nt * 16 + r15) * 16 + ((ks * 4 + kq) ^ r15)) * 8);
            acc0[nt] = __builtin_amdgcn_mfma_f32_16x16x32_bf16(a0, b, acc0[nt], 0, 0, 0);
            acc1[nt] = __builtin_amdgcn_mfma_f32_16x16x32_bf16(a1, b, acc1[nt], 0, 0, 0);
        }
    }

#pragma unroll
    for (int nt = 0; nt < 8; ++nt) {
        const float bv = bias[nt * 16 + r15];
#pragma unroll
        for (int r = 0; r < 4; ++r) {
            if (v0) out[(size_t)(rowbase + kq * 4 + r) * 128 + nt * 16 + r15] =
                f2bf(acc0[nt][r] + bv);
            if (v1) out[(size_t)(rowbase + 16 + kq * 4 + r) * 128 + nt * 16 + r15] =
                f2bf(acc1[nt][r] + bv);
        }
    }
}

// ---------------- fused dual-side SAGE conv GEMM --------------------------
// One launch covers author rows (blocks [0,nbA)) and doc rows (rest).
// Per side: out = maybe_relu(A1b @ W1 + A2b @ W2 + bias), weights LDS-staged
// with 16B-block XOR swizzle. MFMA 16x16x32 bf16 layouts per guide §3.
struct SideParams {
    const u16* A1b; const u16* W1T;
    const u16* A2b; const u16* W2T;
    const float* bias; u16* out;
    int M; int do_relu; int nblocks;
};
__global__ __launch_bounds__(256) void conv_gemm2(SideParams sa, SideParams sd) {
    __shared__ u16 WS[128 * 128];   // 32 KB
    const bool isA = (int)blockIdx.x < sa.nblocks;
    SideParams P = isA ? sa : sd;
    const int bx = isA ? blockIdx.x : blockIdx.x - sa.nblocks;
    const int tid = threadIdx.x;
    const int lane = tid & 63, wave = tid >> 6;
    const int r15 = lane & 15, kq = lane >> 4;
    const int rowbase = bx * 128 + wave * 32;
    const int m0 = rowbase + r15, m1 = rowbase + 16 + r15;
    const bool v0 = rowbase < P.M, v1 = rowbase + 16 < P.M;   // M % 16 == 0

    vf32x4 acc0[8], acc1[8];
#pragma unroll
    for (int i = 0; i < 8; ++i) { acc0[i] = (vf32x4)(0.0f); acc1[i] = (vf32x4)(0.0f); }

#pragma unroll
    for (int mat = 0; mat < 2; ++mat) {
        const u16* WT = mat ? P.W2T : P.W1T;
        if (mat) __syncthreads();          // protect WS before overwrite
#pragma unroll
        for (int i = 0; i < 8; ++i) {
            int L = i * 256 + tid;
            int n = L >> 4, bk = L & 15;
            uint4 v = *(const uint4*)(WT + (size_t)L * 8);
            *(uint4*)(WS + ((size_t)n * 16 + (bk ^ (n & 15))) * 8) = v;
        }
        __syncthreads();

        const u16* Ab = mat ? P.A2b : P.A1b;
#pragma unroll
        for (int ks = 0; ks < 4; ++ks) {
            vbf16x8 a0 = (vbf16x8)(short)0, a1 = (vbf16x8)(short)0;
            if (v0) a0 = *(const vbf16x8*)(Ab + (size_t)m0 * 128 + ks * 32 + kq * 8);
            if (v1) a1 = *(const vbf16x8*)(Ab + (size_t)m1 * 128 + ks * 32 + kq * 8);
#pragma unroll
            for (int nt = 0; nt < 8; ++nt) {
                vbf16x8 b = *(const vbf16x8*)(
                    WS + ((size_t)(nt * 16 + r15) * 16 + ((ks * 4 + kq) ^ r15)) * 8);
                acc0[nt] = __builtin_amdgcn_mfma_f32_16x16x32_bf16(a0, b, acc0[nt], 0, 0, 0);
                acc1[nt] = __builtin_amdgcn_mfma_f32_16x16x32_bf16(a1, b, acc1[nt], 0, 0, 0);
            }
        }
    }

#pragma unroll
    for (int nt = 0; nt < 8; ++nt) {
        const float bv = P.bias[nt * 16 + r15];
#pragma unroll
        for (int r = 0; r < 4; ++r) {
            if (v0) {
                float v = acc0[nt][r] + bv;
                if (P.do_relu) v = fmaxf(v, 0.0f);
                P.out[(size_t)(rowbase + kq * 4 + r) * 128 + nt * 16 + r15] = f2bf(v);
            }
            if (v1) {
                float v = acc1[nt][r] + bv;
                if (P.do_relu) v = fmaxf(v, 0.0f);
                P.out[(size_t)(rowbase + 16 + kq * 4 + r) * 128 + nt * 16 + r15] = f2bf(v);
            }
        }
    }
}

// ---------------- edge scorer: pred[e] = dot(od[i0[e]], oa[i1[e]]) --------
__global__ __launch_bounds__(256) void edge_dot(
    const u16* __restrict__ od, const u16* __restrict__ oa,
    const int* __restrict__ i0, const int* __restrict__ i1,
    float* __restrict__ pred, int EL) {
    int gid = blockIdx.x * 256 + threadIdx.x;
    if (gid >= EL * 16) return;
    int e = gid >> 4, f = gid & 15;
    uint4 x = *(const uint4*)(od + (size_t)i0[e] * 128 + f * 8);
    uint4 y = *(const uint4*)(oa + (size_t)i1[e] * 128 + f * 8);
    float s = 0.0f;
    s += bf2f((u16)(x.x & 0xffff)) * bf2f((u16)(y.x & 0xffff));
    s += bf2f((u16)(x.x >> 16))    * bf2f((u16)(y.x >> 16));
    s += bf2f((u16)(x.y & 0xffff)) * bf2f((u16)(y.y & 0xffff));
    s += bf2f((u16)(x.y >> 16))    * bf2f((u16)(y.y >> 16));
    s += bf2f((u16)(x.z & 0xffff)) * bf2f((u16)(y.z & 0xffff));
    s += bf2f((u16)(x.z >> 16))    * bf2f((u16)(y.z >> 16));
    s += bf2f((u16)(x.w & 0xffff)) * bf2f((u16)(y.w & 0xffff));
    s += bf2f((u16)(x.w >> 16))    * bf2f((u16)(y.w >> 16));
    s += __shfl_xor(s, 1);
    s += __shfl_xor(s, 2);
    s += __shfl_xor(s, 4);
    s += __shfl_xor(s, 8);
    if (f == 0) pred[e] = s;
}

extern "C" void kernel_launch(void* const* d_in, const int* in_sizes, int n_in,
                              void* d_out, int out_size, void* d_ws, size_t ws_size,
                              hipStream_t stream) {
    const float* doc_x    = (const float*)d_in[0];
    const int*   auth_id  = (const int*)d_in[1];
    const int*   eidx     = (const int*)d_in[2];
    const int*   elidx    = (const int*)d_in[3];
    const float* W_doc    = (const float*)d_in[4];
    const float* b_doc    = (const float*)d_in[5];
    const float* emb      = (const float*)d_in[6];
    const float* c1_da_Wl = (const float*)d_in[7];
    const float* c1_da_bl = (const float*)d_in[8];
    const float* c1_da_Wr = (const float*)d_in[9];
    const float* c1_ad_Wl = (const float*)d_in[10];
    const float* c1_ad_bl = (const float*)d_in[11];
    const float* c1_ad_Wr = (const float*)d_in[12];
    const float* c2_da_Wl = (const float*)d_in[13];
    const float* c2_da_bl = (const float*)d_in[14];
    const float* c2_da_Wr = (const float*)d_in[15];
    const float* c2_ad_Wl = (const float*)d_in[16];
    const float* c2_ad_bl = (const float*)d_in[17];
    const float* c2_ad_Wr = (const float*)d_in[18];

    const int ND = in_sizes[0] / 128;
    const int NA = in_sizes[1];
    const int E  = in_sizes[2] / 2;
    const int EL = in_sizes[3] / 2;
    const int* e_src = eidx;        // doc endpoints
    const int* e_dst = eidx + E;    // author endpoints
    const int NBD = (ND + 255) / 256, NBA = (NA + 255) / 256;
    const int BA = (NA + 127) / 128, BD = (ND + 127) / 128;

    // ---- workspace layout ----
    char* base = (char*)d_ws;
    size_t off = 0;
    auto alloc = [&](size_t bytes) {
        void* p = base + off;
        off = (off + bytes + 255) & ~(size_t)255;
        return p;
    };
    u16*  xdoc  = (u16*)alloc((size_t)ND * 128 * 2);   // later reused as o_d
    u16*  xauth = (u16*)alloc((size_t)NA * 128 * 2);   // later reused as o_a
    u16*  hd    = (u16*)alloc((size_t)ND * 128 * 2);
    u16*  ha    = (u16*)alloc((size_t)NA * 128 * 2);
    u16*  aggA  = (u16*)alloc((size_t)NA * 128 * 2);
    u16*  aggD  = (u16*)alloc((size_t)ND * 128 * 2);
    u16*  wt    = (u16*)alloc((size_t)9 * 128 * 128 * 2);
    int*  cnt   = (int*)alloc((size_t)(ND + NA) * 4);      // hist + cursors
    int*  incl  = (int*)alloc((size_t)(ND + NA) * 4);
    int*  bs    = (int*)alloc((size_t)(NBD + NBA) * 4);
    int*  offs_d = (int*)alloc((size_t)(ND + 1) * 4);
    int*  offs_a = (int*)alloc((size_t)(NA + 1) * 4);
    int*  nbr_d = (int*)alloc((size_t)E * 4);
    int*  nbr_a = (int*)alloc((size_t)E * 4);
    (void)ws_size; (void)n_in; (void)out_size;
    u16* od = xdoc;   // layer-2 outputs overwrite layer-0 features
    u16* oa = xauth;

    // ---- CSR build (once; reused by both layers) ----
    hipMemsetAsync(cnt, 0, (size_t)(ND + NA) * 4, stream);
    hist_kernel<<<(E + 255) / 256, 256, 0, stream>>>(e_src, e_dst, cnt, ND, E);
    scan1b<<<NBD + NBA, 256, 0, stream>>>(cnt, incl, bs, ND, NA, NBD);
    scan2b<<<1, 256, 0, stream>>>(bs, NBD, NBA);
    scan3b<<<NBD + NBA, 256, 0, stream>>>(incl, bs, offs_d, offs_a, ND, NA, NBD);
    fill_kernel<<<(E + 255) / 256, 256, 0, stream>>>(
        e_src, e_dst, cnt, offs_d, offs_a, nbr_d, nbr_a, ND, E);

    // ---- prep: weight transposes + author-row gather ----
    TPack tp;
    const float* srcs[9] = {W_doc, c1_da_Wl, c1_da_Wr, c1_ad_Wl, c1_ad_Wr,
                            c2_da_Wl, c2_da_Wr, c2_ad_Wl, c2_ad_Wr};
    for (int i = 0; i < 9; ++i) { tp.src[i] = srcs[i]; tp.dst[i] = wt + (size_t)i * 16384; }
    prep_kernel<<<576 + (NA * 16 + 255) / 256, 256, 0, stream>>>(
        tp, emb, auth_id, xauth, NA);
    const u16 *WTdoc = wt, *WT_c1daL = wt + 16384, *WT_c1daR = wt + 2 * 16384,
              *WT_c1adL = wt + 3 * 16384, *WT_c1adR = wt + 4 * 16384,
              *WT_c2daL = wt + 5 * 16384, *WT_c2daR = wt + 6 * 16384,
              *WT_c2adL = wt + 7 * 16384, *WT_c2adR = wt + 8 * 16384;

    // ---- doc encoder ----
    doc_gemm<<<BD, 256, 0, stream>>>(doc_x, WTdoc, b_doc, xdoc, ND);

    const int aggGrid = ((NA + ND) * 16 + 255) / 256;

    // ---- layer 1 (relu) ----
    agg_mean2<<<aggGrid, 256, 0, stream>>>(
        xdoc, offs_a, nbr_a, aggA, NA, xauth, offs_d, nbr_d, aggD, ND);
    {
        SideParams sa = {aggA, WT_c1daL, xauth, WT_c1daR, c1_da_bl, ha, NA, 1, BA};
        SideParams sd = {aggD, WT_c1adL, xdoc,  WT_c1adR, c1_ad_bl, hd, ND, 1, BD};
        conv_gemm2<<<BA + BD, 256, 0, stream>>>(sa, sd);
    }

    // ---- layer 2 ----
    agg_mean2<<<aggGrid, 256, 0, stream>>>(
        hd, offs_a, nbr_a, aggA, NA, ha, offs_d, nbr_d, aggD, ND);
    {
        SideParams sa = {aggA, WT_c2daL, ha, WT_c2daR, c2_da_bl, oa, NA, 0, BA};
        SideParams sd = {aggD, WT_c2adL, hd, WT_c2adR, c2_ad_bl, od, ND, 0, BD};
        conv_gemm2<<<BA + BD, 256, 0, stream>>>(sa, sd);
    }

    // ---- edge scorer ----
    edge_dot<<<(EL * 16 + 255) / 256, 256, 0, stream>>>(
        od, oa, elidx, elidx + EL, (float*)d_out, EL);
}